// Round 16
// baseline (191.189 us; speedup 1.0000x reference)
//
#include <hip/hip_runtime.h>
#include <hip/hip_bf16.h>
#include <stdint.h>

// MHSA fused: B=4, N=2048, D=1024, H=16, Dh=64
// cvt(x)/tcvt(w) -> gemm_qkv(128^2 m97, Q pre-scaled by EXPC) ->
// attn(no-shift softmax, wave-staggered halves, MFMA-lsum) -> gemm_out(128^2)

typedef __attribute__((ext_vector_type(8))) __bf16 bf16x8;
typedef __attribute__((ext_vector_type(4))) __bf16 bf16x4;
typedef __attribute__((ext_vector_type(4))) float f32x4;
typedef __attribute__((ext_vector_type(16))) float f32x16;
typedef __attribute__((ext_vector_type(4))) unsigned int u32x4;

// 0.125 (head-dim scale) * log2(e). Q is pre-scaled by this in the QKV epilogue,
// so the attn exp arg is the RAW QK^T MFMA output: P = exp2(sa), no shift.
// P in [2^-9, 2^9]: bf16-safe; softmax normalization cancels any fixed scale.
#define EXPC 0.18033688011112042f

static __device__ __forceinline__ void gload_lds16(const void* g, void* s) {
  __builtin_amdgcn_global_load_lds(
      (__attribute__((address_space(1))) unsigned int*)g,
      (__attribute__((address_space(3))) unsigned int*)s, 16, 0, 0);
}

// ---------------- f32 -> bf16 flat convert (vectorized) ----------------
__global__ void k_cvt(const float* __restrict__ src, __bf16* __restrict__ dst, int n4) {
  int i = blockIdx.x * blockDim.x + threadIdx.x;
  if (i >= n4) return;
  float4 v = reinterpret_cast<const float4*>(src)[i];
  bf16x4 o = { (__bf16)v.x, (__bf16)v.y, (__bf16)v.z, (__bf16)v.w };
  *reinterpret_cast<bf16x4*>(dst + (size_t)i * 4) = o;
}

// ---------------- transpose + convert: dst[c][r] = src[r][c], src is Hs x W ----
__global__ void k_tcvt(const float* __restrict__ src, __bf16* __restrict__ dst, int W, int Hs) {
  __shared__ float tile[32][33];
  int tx = threadIdx.x, ty = threadIdx.y;  // 32 x 8
  int x = blockIdx.x * 32 + tx;
  int y0 = blockIdx.y * 32;
  for (int j = ty; j < 32; j += 8) tile[j][tx] = src[(size_t)(y0 + j) * W + x];
  __syncthreads();
  int xo = y0 + tx;
  int yo = blockIdx.x * 32;
  for (int j = ty; j < 32; j += 8) dst[(size_t)(yo + j) * Hs + xo] = (__bf16)tile[tx][j];
}

// ---------------- m97-structure GEMM core (128^2): proven r7/r12 ----------------
static __device__ __forceinline__ void gemm_core(
    const __bf16* __restrict__ A, const __bf16* __restrict__ BT, int K,
    int m0, int n0, f32x4 acc[4][4], __bf16* As, __bf16* Bs) {
  const int tid = threadIdx.x;
  const int lane = tid & 63, w = tid >> 6;
  const int fr = lane & 15, fq = lane >> 4;
  const int srow = lane >> 2, scol = (lane & 3) * 8;
  const int wr = (w >> 1) * 64, wc = (w & 1) * 64;
#pragma unroll
  for (int mi = 0; mi < 4; ++mi)
#pragma unroll
    for (int nj = 0; nj < 4; ++nj) acc[mi][nj] = (f32x4){0.f, 0.f, 0.f, 0.f};

  for (int ko = 0; ko < K; ko += 32) {
#pragma unroll
    for (int i = 0; i < 2; ++i) {
      int rb = w * 32 + i * 16;
      gload_lds16(A + (size_t)(m0 + rb + srow) * K + ko + scol, As + rb * 32);
      gload_lds16(BT + (size_t)(n0 + rb + srow) * K + ko + scol, Bs + rb * 32);
    }
    __syncthreads();
    bf16x8 af[4], bfv[4];
#pragma unroll
    for (int mi = 0; mi < 4; ++mi)
      af[mi] = *(const bf16x8*)(As + (wr + mi * 16 + fr) * 32 + fq * 8);
#pragma unroll
    for (int nj = 0; nj < 4; ++nj)
      bfv[nj] = *(const bf16x8*)(Bs + (wc + nj * 16 + fr) * 32 + fq * 8);
#pragma unroll
    for (int mi = 0; mi < 4; ++mi)
#pragma unroll
      for (int nj = 0; nj < 4; ++nj)
        acc[mi][nj] = __builtin_amdgcn_mfma_f32_16x16x32_bf16(af[mi], bfv[nj], acc[mi][nj], 0, 0, 0);
    __syncthreads();
  }
}

// C cols 0..3071: [q | k | v]. q (scaled by EXPC), k -> [bh][n][64]; v -> [bh][64][n]
// 128^2 tile, grid 64x24 = 1536 blocks (full machine coverage, 2-3 blocks/CU).
__global__ __launch_bounds__(256) void k_gemm_qkv(
    const __bf16* __restrict__ A, const __bf16* __restrict__ BT,
    __bf16* __restrict__ qb, __bf16* __restrict__ kb, __bf16* __restrict__ vb) {
  __shared__ __align__(16) __bf16 As[128 * 32];
  __shared__ __align__(16) __bf16 Bs[128 * 32];
  f32x4 acc[4][4];
  int m0 = blockIdx.x * 128, n0 = blockIdx.y * 128;
  gemm_core(A, BT, 1024, m0, n0, acc, As, Bs);
  const int lane = threadIdx.x & 63, w = threadIdx.x >> 6;
  const int fr = lane & 15, fq = lane >> 4;
  const int wr = (w >> 1) * 64, wc = (w & 1) * 64;
  const int which = n0 >> 10;  // 128-col tile never crosses a q/k/v boundary
#pragma unroll
  for (int mi = 0; mi < 4; ++mi) {
#pragma unroll
    for (int nj = 0; nj < 4; ++nj) {
      int row = m0 + wr + mi * 16 + fq * 4;          // token index (4 consecutive)
      int col = n0 + wc + nj * 16 + fr;              // qkv column
      int rem = col & 1023, h = rem >> 6, d = rem & 63;
      int bb = row >> 11, n = row & 2047;            // row..row+3 stay in one b
      int bh = bb * 16 + h;
      if (which == 2) {
        bf16x4 pk = { (__bf16)acc[mi][nj][0], (__bf16)acc[mi][nj][1],
                      (__bf16)acc[mi][nj][2], (__bf16)acc[mi][nj][3] };
        *reinterpret_cast<bf16x4*>(vb + ((size_t)bh * 64 + d) * 2048 + n) = pk;
      } else if (which == 0) {   // q: pre-scale by EXPC (attn exp arg = raw MFMA out)
#pragma unroll
        for (int j = 0; j < 4; ++j)
          qb[((size_t)bh * 2048 + (n + j)) * 64 + d] = (__bf16)(acc[mi][nj][j] * EXPC);
      } else {
#pragma unroll
        for (int j = 0; j < 4; ++j)
          kb[((size_t)bh * 2048 + (n + j)) * 64 + d] = (__bf16)acc[mi][nj][j];
      }
    }
  }
}

// gemm_out on the 128^2 m97 core: grid 64x8 = 512 blocks (full machine coverage).
__global__ __launch_bounds__(256) void k_gemm_out(
    const __bf16* __restrict__ A, const __bf16* __restrict__ BT, float* __restrict__ C) {
  __shared__ __align__(16) __bf16 As[128 * 32];
  __shared__ __align__(16) __bf16 Bs[128 * 32];
  f32x4 acc[4][4];
  int m0 = blockIdx.x * 128, n0 = blockIdx.y * 128;
  gemm_core(A, BT, 1024, m0, n0, acc, As, Bs);
  const int lane = threadIdx.x & 63, w = threadIdx.x >> 6;
  const int fr = lane & 15, fq = lane >> 4;
  const int wr = (w >> 1) * 64, wc = (w & 1) * 64;
#pragma unroll
  for (int mi = 0; mi < 4; ++mi)
#pragma unroll
    for (int nj = 0; nj < 4; ++nj)
#pragma unroll
      for (int j = 0; j < 4; ++j)
        C[(size_t)(m0 + wr + mi * 16 + fq * 4 + j) * 1024 + n0 + wc + nj * 16 + fr] =
            acc[mi][nj][j];
}

// ---------------- flash attention: no-shift softmax, staggered halves, MFMA-lsum --
// (r15, unchanged) waves 0/1 process halves {0,1}; waves 2/3 {1,0} -> at any instant
// half the waves issue MFMA while the others issue exp VALU. P = exp2(sa) directly
// (Q carries the EXPC scale). Row-sums on the MFMA pipe (lacc = mfma(pa, ones, lacc)).
__global__ __launch_bounds__(256, 4) void k_attn(
    const __bf16* __restrict__ qb, const __bf16* __restrict__ kb,
    const __bf16* __restrict__ vb, __bf16* __restrict__ ao) {
  __shared__ __align__(16) __bf16 Ks[2][64 * 64];   // [key][d], swizzled
  __shared__ __align__(16) __bf16 Vs[2][64 * 64];   // [d][key], swizzled (vb pre-transposed)
  const int tid = threadIdx.x, lane = tid & 63, wid = tid >> 6;
  const int r31 = lane & 31, hi = lane >> 5;
  const int lsw = (lane & 7) ^ ((lane >> 3) & 3);
  const int hord = (wid >> 1) & 1;                  // half-order stagger per wave-pair
  const int bh = blockIdx.x & 63, qblk = blockIdx.x >> 6;
  const __bf16* kbase = kb + (size_t)bh * 2048 * 64;
  const __bf16* vbase = vb + (size_t)bh * 64 * 2048;

  const int nbase = qblk * 128 + wid * 32;
  const __bf16* qptr = qb + ((size_t)bh * 2048 + nbase + r31) * 64;
  bf16x8 qf[4];
#pragma unroll
  for (int dd = 0; dd < 4; ++dd)
    qf[dd] = *(const bf16x8*)(qptr + dd * 16 + hi * 8);

  const u32x4 onesw = {0x3F803F80u, 0x3F803F80u, 0x3F803F80u, 0x3F803F80u};
  const bf16x8 onesv = __builtin_bit_cast(bf16x8, onesw);

  f32x16 o0, o1, lacc;  // O accum + P row-sum accum: rows q=crow(r,hi)
#pragma unroll
  for (int r = 0; r < 16; ++r) { o0[r] = 0.f; o1[r] = 0.f; lacc[r] = 0.f; }

  auto stage = [&](int buf, int j0) {
#pragma unroll
    for (int p2 = 0; p2 < 2; ++p2) {
      int row = p2 * 32 + (tid >> 3);
      int sc = (tid & 7) ^ (row & 7) ^ ((row >> 3) & 3);
      int dst = p2 * 2048 + wid * 512;
      gload_lds16(kbase + (size_t)(j0 + row) * 64 + sc * 8, &Ks[buf][dst]);
      gload_lds16(vbase + (size_t)row * 2048 + j0 + sc * 8, &Vs[buf][dst]);
    }
  };

  stage(0, 0);
  __syncthreads();

  for (int kt = 0; kt < 32; ++kt) {
    const int cur = kt & 1;
    if (kt < 31) stage(cur ^ 1, (kt + 1) * 64);

#pragma unroll
    for (int hx = 0; hx < 2; ++hx) {
      const int h2 = hx ^ hord;                // staggered half order across waves
      const int kro = h2 * 32;

      // ---- S^T (half) = K Q^T (Q carries the EXPC scale) ----
      f32x16 sa;
#pragma unroll
      for (int r = 0; r < 16; ++r) sa[r] = 0.f;
      __builtin_amdgcn_s_setprio(1);
#pragma unroll
      for (int dd = 0; dd < 4; ++dd) {
        bf16x8 kf = *(const bf16x8*)(&Ks[cur][(kro + r31) * 64 + (((dd * 2 + hi) ^ lsw) << 3)]);
        sa = __builtin_amdgcn_mfma_f32_32x32x16_bf16(kf, qf[dd], sa, 0, 0, 0);
      }
      __builtin_amdgcn_s_setprio(0);

      // ---- P = exp2(sa) directly; pack pairs via cvt_pk ----
      unsigned pw[8];
#pragma unroll
      for (int r = 0; r < 8; ++r) {
        float e0 = __builtin_amdgcn_exp2f(sa[2 * r]);
        float e1 = __builtin_amdgcn_exp2f(sa[2 * r + 1]);
        asm("v_cvt_pk_bf16_f32 %0, %1, %2" : "=v"(pw[r]) : "v"(e0), "v"(e1));
      }

      // ---- O += P V; lacc += P*1 (row-sums on the MFMA pipe) ----
      __builtin_amdgcn_s_setprio(1);
#define PVSTEP(W0, W1, W2, W3, KK) do {                                              \
        unsigned a0 = (W0), a1 = (W1), b0 = (W2), b1 = (W3);                         \
        asm("v_permlane32_swap_b32 %0, %1" : "+v"(a0), "+v"(b0));                    \
        asm("v_permlane32_swap_b32 %0, %1" : "+v"(a1), "+v"(b1));                    \
        u32x4 fw = {a0, a1, b0, b1};                                                 \
        bf16x8 pa = __builtin_bit_cast(bf16x8, fw);                                  \
        bf16x8 v0 = *(const bf16x8*)(&Vs[cur][r31 * 64 + ((((KK) * 2 + hi) ^ lsw) << 3)]); \
        bf16x8 v1 = *(const bf16x8*)(&Vs[cur][(32 + r31) * 64 + ((((KK) * 2 + hi) ^ lsw) << 3)]); \
        o0 = __builtin_amdgcn_mfma_f32_32x32x16_bf16(pa, v0, o0, 0, 0, 0);           \
        o1 = __builtin_amdgcn_mfma_f32_32x32x16_bf16(pa, v1, o1, 0, 0, 0);           \
        lacc = __builtin_amdgcn_mfma_f32_32x32x16_bf16(pa, onesv, lacc, 0, 0, 0);    \
      } while (0)
      PVSTEP(pw[0], pw[1], pw[2], pw[3], 2 * h2);
      PVSTEP(pw[4], pw[5], pw[6], pw[7], 2 * h2 + 1);
#undef PVSTEP
      __builtin_amdgcn_s_setprio(0);
    }

    __syncthreads();
  }

  // ---- epilogue: shfl-free normalize + store (lacc rows match o rows) ----
  const int b = bh >> 4, h = bh & 15;
  __bf16* abase = ao + ((size_t)b * 2048 + nbase) * 1024 + h * 64 + r31;
#pragma unroll
  for (int r = 0; r < 16; ++r) {
    int qrow = (r & 3) + 8 * (r >> 2) + 4 * hi;
    float ir = 1.0f / lacc[r];
    abase[(size_t)qrow * 1024] = (__bf16)(o0[r] * ir);
    abase[(size_t)qrow * 1024 + 32] = (__bf16)(o1[r] * ir);
  }
}

extern "C" void kernel_launch(void* const* d_in, const int* in_sizes, int n_in,
                              void* d_out, int out_size, void* d_ws, size_t ws_size,
                              hipStream_t stream) {
  (void)in_sizes; (void)n_in; (void)out_size; (void)ws_size;
  const float* x = (const float*)d_in[0];      // [4,2048,1024]
  const float* w_qkv = (const float*)d_in[1];  // [1024,3072]
  const float* w_out = (const float*)d_in[2];  // [1024,1024]
  float* out = (float*)d_out;                  // [4,2048,1024]

  char* p = (char*)d_ws;
  __bf16* xb    = (__bf16*)p; p += (size_t)8192 * 1024 * 2;  // x bf16 [8192][1024]
  __bf16* wqkvT = (__bf16*)p; p += (size_t)3072 * 1024 * 2;  // w_qkv^T [3072][1024]
  __bf16* woutT = (__bf16*)p; p += (size_t)1024 * 1024 * 2;  // w_out^T [1024][1024]
  __bf16* qb    = (__bf16*)p; p += (size_t)64 * 2048 * 64 * 2;  // [bh][n][d], q*EXPC
  __bf16* kb    = (__bf16*)p; p += (size_t)64 * 2048 * 64 * 2;  // [bh][n][d]
  __bf16* vb    = (__bf16*)p; p += (size_t)64 * 64 * 2048 * 2;  // [bh][d][n]
  __bf16* ao    = (__bf16*)p; p += (size_t)8192 * 1024 * 2;     // [b*n][h*d]

  k_cvt<<<8192, 256, 0, stream>>>(x, xb, 2097152);
  k_tcvt<<<dim3(96, 32), dim3(32, 8), 0, stream>>>(w_qkv, wqkvT, 3072, 1024);
  k_tcvt<<<dim3(32, 32), dim3(32, 8), 0, stream>>>(w_out, woutT, 1024, 1024);
  k_gemm_qkv<<<dim3(64, 24), 256, 0, stream>>>(xb, wqkvT, qb, kb, vb);
  k_attn<<<dim3(1024), dim3(256), 0, stream>>>(qb, kb, vb, ao);
  k_gemm_out<<<dim3(64, 8), 256, 0, stream>>>(ao, woutT, out);
}

// Round 18
// 186.476 us; speedup vs baseline: 1.0253x; 1.0253x over previous
//
#include <hip/hip_runtime.h>
#include <hip/hip_bf16.h>
#include <stdint.h>

// MHSA fused: B=4, N=2048, D=1024, H=16, Dh=64
// k_prep(cvt+tcvt fused) -> gemm_qkv(128^2 m97, Q pre-scaled by EXPC) ->
// attn(r16-verbatim: no-shift softmax, staggered halves, MFMA-lsum, setprio) -> gemm_out

typedef __attribute__((ext_vector_type(8))) __bf16 bf16x8;
typedef __attribute__((ext_vector_type(4))) __bf16 bf16x4;
typedef __attribute__((ext_vector_type(4))) float f32x4;
typedef __attribute__((ext_vector_type(16))) float f32x16;
typedef __attribute__((ext_vector_type(4))) unsigned int u32x4;

// 0.125 (head-dim scale) * log2(e). Q pre-scaled by this in the QKV epilogue ->
// attn exp arg = raw QK^T MFMA output; P in [2^-9, 2^9], scale cancels in softmax.
#define EXPC 0.18033688011112042f

static __device__ __forceinline__ void gload_lds16(const void* g, void* s) {
  __builtin_amdgcn_global_load_lds(
      (__attribute__((address_space(1))) unsigned int*)g,
      (__attribute__((address_space(3))) unsigned int*)s, 16, 0, 0);
}

// ---------------- fused prep: cvt(x) + tcvt(w_qkv) + tcvt(w_out) ----------------
// blocks [0,8192): x f32->bf16 (256 thr x float4)
// blocks [8192,11264): w_qkv transpose-cvt (96x32 tile grid)
// blocks [11264,12288): w_out transpose-cvt (32x32 tile grid)
__global__ __launch_bounds__(256) void k_prep(
    const float* __restrict__ x, const float* __restrict__ wq, const float* __restrict__ wo,
    __bf16* __restrict__ xb, __bf16* __restrict__ wqT, __bf16* __restrict__ woT) {
  const int blk = blockIdx.x;
  if (blk < 8192) {
    int i = blk * 256 + threadIdx.x;
    float4 v = reinterpret_cast<const float4*>(x)[i];
    bf16x4 o = { (__bf16)v.x, (__bf16)v.y, (__bf16)v.z, (__bf16)v.w };
    *reinterpret_cast<bf16x4*>(xb + (size_t)i * 4) = o;
    return;
  }
  __shared__ float tile[32][33];
  const float* src; __bf16* dst; int W, bx, by;
  if (blk < 8192 + 3072) { int b = blk - 8192; src = wq; dst = wqT; W = 3072; bx = b % 96; by = b / 96; }
  else                   { int b = blk - 11264; src = wo; dst = woT; W = 1024; bx = b % 32; by = b / 32; }
  const int tx = threadIdx.x & 31, ty = threadIdx.x >> 5;  // 32 x 8
  const int xc = bx * 32 + tx, y0 = by * 32;
  for (int j = ty; j < 32; j += 8) tile[j][tx] = src[(size_t)(y0 + j) * W + xc];
  __syncthreads();
  const int xo = y0 + tx, yo = bx * 32;
  for (int j = ty; j < 32; j += 8) dst[(size_t)(yo + j) * 1024 + xo] = (__bf16)tile[tx][j];
}

// ---------------- m97-structure GEMM core (128^2): proven r7/r12 ----------------
static __device__ __forceinline__ void gemm_core(
    const __bf16* __restrict__ A, const __bf16* __restrict__ BT, int K,
    int m0, int n0, f32x4 acc[4][4], __bf16* As, __bf16* Bs) {
  const int tid = threadIdx.x;
  const int lane = tid & 63, w = tid >> 6;
  const int fr = lane & 15, fq = lane >> 4;
  const int srow = lane >> 2, scol = (lane & 3) * 8;
  const int wr = (w >> 1) * 64, wc = (w & 1) * 64;
#pragma unroll
  for (int mi = 0; mi < 4; ++mi)
#pragma unroll
    for (int nj = 0; nj < 4; ++nj) acc[mi][nj] = (f32x4){0.f, 0.f, 0.f, 0.f};

  for (int ko = 0; ko < K; ko += 32) {
#pragma unroll
    for (int i = 0; i < 2; ++i) {
      int rb = w * 32 + i * 16;
      gload_lds16(A + (size_t)(m0 + rb + srow) * K + ko + scol, As + rb * 32);
      gload_lds16(BT + (size_t)(n0 + rb + srow) * K + ko + scol, Bs + rb * 32);
    }
    __syncthreads();
    bf16x8 af[4], bfv[4];
#pragma unroll
    for (int mi = 0; mi < 4; ++mi)
      af[mi] = *(const bf16x8*)(As + (wr + mi * 16 + fr) * 32 + fq * 8);
#pragma unroll
    for (int nj = 0; nj < 4; ++nj)
      bfv[nj] = *(const bf16x8*)(Bs + (wc + nj * 16 + fr) * 32 + fq * 8);
#pragma unroll
    for (int mi = 0; mi < 4; ++mi)
#pragma unroll
      for (int nj = 0; nj < 4; ++nj)
        acc[mi][nj] = __builtin_amdgcn_mfma_f32_16x16x32_bf16(af[mi], bfv[nj], acc[mi][nj], 0, 0, 0);
    __syncthreads();
  }
}

// C cols 0..3071: [q | k | v]. q (scaled by EXPC), k -> [bh][n][64]; v -> [bh][64][n]
__global__ __launch_bounds__(256) void k_gemm_qkv(
    const __bf16* __restrict__ A, const __bf16* __restrict__ BT,
    __bf16* __restrict__ qb, __bf16* __restrict__ kb, __bf16* __restrict__ vb) {
  __shared__ __align__(16) __bf16 As[128 * 32];
  __shared__ __align__(16) __bf16 Bs[128 * 32];
  f32x4 acc[4][4];
  int m0 = blockIdx.x * 128, n0 = blockIdx.y * 128;
  gemm_core(A, BT, 1024, m0, n0, acc, As, Bs);
  const int lane = threadIdx.x & 63, w = threadIdx.x >> 6;
  const int fr = lane & 15, fq = lane >> 4;
  const int wr = (w >> 1) * 64, wc = (w & 1) * 64;
  const int which = n0 >> 10;
#pragma unroll
  for (int mi = 0; mi < 4; ++mi) {
#pragma unroll
    for (int nj = 0; nj < 4; ++nj) {
      int row = m0 + wr + mi * 16 + fq * 4;
      int col = n0 + wc + nj * 16 + fr;
      int rem = col & 1023, h = rem >> 6, d = rem & 63;
      int bb = row >> 11, n = row & 2047;
      int bh = bb * 16 + h;
      if (which == 2) {
        bf16x4 pk = { (__bf16)acc[mi][nj][0], (__bf16)acc[mi][nj][1],
                      (__bf16)acc[mi][nj][2], (__bf16)acc[mi][nj][3] };
        *reinterpret_cast<bf16x4*>(vb + ((size_t)bh * 64 + d) * 2048 + n) = pk;
      } else if (which == 0) {   // q: pre-scale by EXPC
#pragma unroll
        for (int j = 0; j < 4; ++j)
          qb[((size_t)bh * 2048 + (n + j)) * 64 + d] = (__bf16)(acc[mi][nj][j] * EXPC);
      } else {
#pragma unroll
        for (int j = 0; j < 4; ++j)
          kb[((size_t)bh * 2048 + (n + j)) * 64 + d] = (__bf16)acc[mi][nj][j];
      }
    }
  }
}

__global__ __launch_bounds__(256) void k_gemm_out(
    const __bf16* __restrict__ A, const __bf16* __restrict__ BT, float* __restrict__ C) {
  __shared__ __align__(16) __bf16 As[128 * 32];
  __shared__ __align__(16) __bf16 Bs[128 * 32];
  f32x4 acc[4][4];
  int m0 = blockIdx.x * 128, n0 = blockIdx.y * 128;
  gemm_core(A, BT, 1024, m0, n0, acc, As, Bs);
  const int lane = threadIdx.x & 63, w = threadIdx.x >> 6;
  const int fr = lane & 15, fq = lane >> 4;
  const int wr = (w >> 1) * 64, wc = (w & 1) * 64;
#pragma unroll
  for (int mi = 0; mi < 4; ++mi)
#pragma unroll
    for (int nj = 0; nj < 4; ++nj)
#pragma unroll
      for (int j = 0; j < 4; ++j)
        C[(size_t)(m0 + wr + mi * 16 + fq * 4 + j) * 1024 + n0 + wc + nj * 16 + fr] =
            acc[mi][nj][j];
}

// ---------------- flash attention: r16-VERBATIM (setprio restored) ----------------
// Bisection arm: only k_prep fusion differs from the r16-passing build. If this
// fails, the fusion is convicted; if it passes, setprio-removal was the r17 bug
// (compiler hazard around the non-volatile asm cluster) and is permanently banned.
__global__ __launch_bounds__(256, 4) void k_attn(
    const __bf16* __restrict__ qb, const __bf16* __restrict__ kb,
    const __bf16* __restrict__ vb, __bf16* __restrict__ ao) {
  __shared__ __align__(16) __bf16 Ks[2][64 * 64];   // [key][d], swizzled
  __shared__ __align__(16) __bf16 Vs[2][64 * 64];   // [d][key], swizzled (vb pre-transposed)
  const int tid = threadIdx.x, lane = tid & 63, wid = tid >> 6;
  const int r31 = lane & 31, hi = lane >> 5;
  const int lsw = (lane & 7) ^ ((lane >> 3) & 3);
  const int hord = (wid >> 1) & 1;                  // half-order stagger per wave-pair
  const int bh = blockIdx.x & 63, qblk = blockIdx.x >> 6;
  const __bf16* kbase = kb + (size_t)bh * 2048 * 64;
  const __bf16* vbase = vb + (size_t)bh * 64 * 2048;

  const int nbase = qblk * 128 + wid * 32;
  const __bf16* qptr = qb + ((size_t)bh * 2048 + nbase + r31) * 64;
  bf16x8 qf[4];
#pragma unroll
  for (int dd = 0; dd < 4; ++dd)
    qf[dd] = *(const bf16x8*)(qptr + dd * 16 + hi * 8);

  const u32x4 onesw = {0x3F803F80u, 0x3F803F80u, 0x3F803F80u, 0x3F803F80u};
  const bf16x8 onesv = __builtin_bit_cast(bf16x8, onesw);

  f32x16 o0, o1, lacc;  // O accum + P row-sum accum: rows q=crow(r,hi)
#pragma unroll
  for (int r = 0; r < 16; ++r) { o0[r] = 0.f; o1[r] = 0.f; lacc[r] = 0.f; }

  auto stage = [&](int buf, int j0) {
#pragma unroll
    for (int p2 = 0; p2 < 2; ++p2) {
      int row = p2 * 32 + (tid >> 3);
      int sc = (tid & 7) ^ (row & 7) ^ ((row >> 3) & 3);
      int dst = p2 * 2048 + wid * 512;
      gload_lds16(kbase + (size_t)(j0 + row) * 64 + sc * 8, &Ks[buf][dst]);
      gload_lds16(vbase + (size_t)row * 2048 + j0 + sc * 8, &Vs[buf][dst]);
    }
  };

  stage(0, 0);
  __syncthreads();

  for (int kt = 0; kt < 32; ++kt) {
    const int cur = kt & 1;
    if (kt < 31) stage(cur ^ 1, (kt + 1) * 64);

#pragma unroll
    for (int hx = 0; hx < 2; ++hx) {
      const int h2 = hx ^ hord;                // staggered half order across waves
      const int kro = h2 * 32;

      // ---- S^T (half) = K Q^T (Q carries the EXPC scale) ----
      f32x16 sa;
#pragma unroll
      for (int r = 0; r < 16; ++r) sa[r] = 0.f;
      __builtin_amdgcn_s_setprio(1);
#pragma unroll
      for (int dd = 0; dd < 4; ++dd) {
        bf16x8 kf = *(const bf16x8*)(&Ks[cur][(kro + r31) * 64 + (((dd * 2 + hi) ^ lsw) << 3)]);
        sa = __builtin_amdgcn_mfma_f32_32x32x16_bf16(kf, qf[dd], sa, 0, 0, 0);
      }
      __builtin_amdgcn_s_setprio(0);

      // ---- P = exp2(sa) directly; pack pairs via cvt_pk ----
      unsigned pw[8];
#pragma unroll
      for (int r = 0; r < 8; ++r) {
        float e0 = __builtin_amdgcn_exp2f(sa[2 * r]);
        float e1 = __builtin_amdgcn_exp2f(sa[2 * r + 1]);
        asm("v_cvt_pk_bf16_f32 %0, %1, %2" : "=v"(pw[r]) : "v"(e0), "v"(e1));
      }

      // ---- O += P V; lacc += P*1 (row-sums on the MFMA pipe) ----
      __builtin_amdgcn_s_setprio(1);
#define PVSTEP(W0, W1, W2, W3, KK) do {                                              \
        unsigned a0 = (W0), a1 = (W1), b0 = (W2), b1 = (W3);                         \
        asm("v_permlane32_swap_b32 %0, %1" : "+v"(a0), "+v"(b0));                    \
        asm("v_permlane32_swap_b32 %0, %1" : "+v"(a1), "+v"(b1));                    \
        u32x4 fw = {a0, a1, b0, b1};                                                 \
        bf16x8 pa = __builtin_bit_cast(bf16x8, fw);                                  \
        bf16x8 v0 = *(const bf16x8*)(&Vs[cur][r31 * 64 + ((((KK) * 2 + hi) ^ lsw) << 3)]); \
        bf16x8 v1 = *(const bf16x8*)(&Vs[cur][(32 + r31) * 64 + ((((KK) * 2 + hi) ^ lsw) << 3)]); \
        o0 = __builtin_amdgcn_mfma_f32_32x32x16_bf16(pa, v0, o0, 0, 0, 0);           \
        o1 = __builtin_amdgcn_mfma_f32_32x32x16_bf16(pa, v1, o1, 0, 0, 0);           \
        lacc = __builtin_amdgcn_mfma_f32_32x32x16_bf16(pa, onesv, lacc, 0, 0, 0);    \
      } while (0)
      PVSTEP(pw[0], pw[1], pw[2], pw[3], 2 * h2);
      PVSTEP(pw[4], pw[5], pw[6], pw[7], 2 * h2 + 1);
#undef PVSTEP
      __builtin_amdgcn_s_setprio(0);
    }

    __syncthreads();
  }

  // ---- epilogue: shfl-free normalize + store (lacc rows match o rows) ----
  const int b = bh >> 4, h = bh & 15;
  __bf16* abase = ao + ((size_t)b * 2048 + nbase) * 1024 + h * 64 + r31;
#pragma unroll
  for (int r = 0; r < 16; ++r) {
    int qrow = (r & 3) + 8 * (r >> 2) + 4 * hi;
    float ir = 1.0f / lacc[r];
    abase[(size_t)qrow * 1024] = (__bf16)(o0[r] * ir);
    abase[(size_t)qrow * 1024 + 32] = (__bf16)(o1[r] * ir);
  }
}

extern "C" void kernel_launch(void* const* d_in, const int* in_sizes, int n_in,
                              void* d_out, int out_size, void* d_ws, size_t ws_size,
                              hipStream_t stream) {
  (void)in_sizes; (void)n_in; (void)out_size; (void)ws_size;
  const float* x = (const float*)d_in[0];      // [4,2048,1024]
  const float* w_qkv = (const float*)d_in[1];  // [1024,3072]
  const float* w_out = (const float*)d_in[2];  // [1024,1024]
  float* out = (float*)d_out;                  // [4,2048,1024]

  char* p = (char*)d_ws;
  __bf16* xb    = (__bf16*)p; p += (size_t)8192 * 1024 * 2;  // x bf16 [8192][1024]
  __bf16* wqkvT = (__bf16*)p; p += (size_t)3072 * 1024 * 2;  // w_qkv^T [3072][1024]
  __bf16* woutT = (__bf16*)p; p += (size_t)1024 * 1024 * 2;  // w_out^T [1024][1024]
  __bf16* qb    = (__bf16*)p; p += (size_t)64 * 2048 * 64 * 2;  // [bh][n][d], q*EXPC
  __bf16* kb    = (__bf16*)p; p += (size_t)64 * 2048 * 64 * 2;  // [bh][n][d]
  __bf16* vb    = (__bf16*)p; p += (size_t)64 * 64 * 2048 * 2;  // [bh][d][n]
  __bf16* ao    = (__bf16*)p; p += (size_t)8192 * 1024 * 2;     // [b*n][h*d]

  k_prep<<<12288, 256, 0, stream>>>(x, w_qkv, w_out, xb, wqkvT, woutT);
  k_gemm_qkv<<<dim3(64, 24), 256, 0, stream>>>(xb, wqkvT, qb, kb, vb);
  k_attn<<<dim3(1024), 256, 0, stream>>>(qb, kb, vb, ao);
  k_gemm_out<<<dim3(64, 8), 256, 0, stream>>>(ao, woutT, out);
}